// Round 2
// baseline (66.366 us; speedup 1.0000x reference)
//
#include <hip/hip_runtime.h>
#include <math.h>

// VisionPooler: B=32, SEQ=2520 (84x30 grid), HIDDEN=768, OUT_LEN=280, k=3.
// out = concat( [B,280,768] pooled f32 , [B,280] mask-as-f32 ).
// ws layout: int max_x[32] @0 ; int counts[32*280] @256B ; int lists[32*280*16].
// ws bytes needed: 256 + 35840 + 573440 = 609,536.

#define NB   32
#define SEQL 2520
#define HID  768
#define OUTL 280
#define CAP  16   // max patches tracked per bucket (actual = 9)

__global__ void k_maxx(const int* __restrict__ pos, int* __restrict__ max_x) {
    __shared__ int sm[256];
    const int b = blockIdx.x;
    const int* p = pos + (size_t)b * SEQL * 2;
    int m = 0;
    for (int s = threadIdx.x; s < SEQL; s += blockDim.x) {
        int x = p[2 * s];
        if (x < 0) x = 0;
        if (x > m) m = x;
    }
    sm[threadIdx.x] = m;
    __syncthreads();
    for (int off = 128; off > 0; off >>= 1) {
        if ((int)threadIdx.x < off) {
            int o = sm[threadIdx.x + off];
            if (o > sm[threadIdx.x]) sm[threadIdx.x] = o;
        }
        __syncthreads();
    }
    if (threadIdx.x == 0) max_x[b] = sm[0] + 1;
}

__global__ void k_build(const int* __restrict__ pos, const int* __restrict__ max_x,
                        int* __restrict__ counts, int* __restrict__ lists, int k) {
    int idx = blockIdx.x * blockDim.x + threadIdx.x;
    if (idx >= NB * SEQL) return;
    int b = idx / SEQL;
    int s = idx - b * SEQL;
    int x = pos[2 * idx];     if (x < 0) x = 0;
    int y = pos[2 * idx + 1]; if (y < 0) y = 0;
    int mxk = max_x[b] / k;
    int seg = x / k + mxk * (y / k);
    if (seg < 0 || seg >= OUTL) return;   // jax segment_sum drops out-of-range ids
    int slot = atomicAdd(&counts[b * OUTL + seg], 1);
    if (slot < CAP) lists[(b * OUTL + seg) * CAP + slot] = s;
}

// One block per (bucket l, batch b). 192 threads, each owns one float4 of HID.
__global__ void __launch_bounds__(192)
k_pool(const float* __restrict__ hs, const int* __restrict__ padding,
       const int* __restrict__ counts, const int* __restrict__ lists,
       float* __restrict__ out, float* __restrict__ out_mask, float scale) {
    __shared__ int idxs[CAP];
    __shared__ int padf[CAP];
    __shared__ int s_cnt;
    const int l = blockIdx.x;
    const int b = blockIdx.y;
    const int bl = b * OUTL + l;

    if (threadIdx.x == 0) {
        int c  = counts[bl];
        int cc = c < CAP ? c : CAP;
        for (int i = 0; i < cc; ++i) idxs[i] = lists[bl * CAP + i];
        // insertion sort ascending -> deterministic summation order
        for (int i = 1; i < cc; ++i) {
            int v = idxs[i], j = i - 1;
            while (j >= 0 && idxs[j] > v) { idxs[j + 1] = idxs[j]; --j; }
            idxs[j + 1] = v;
        }
        s_cnt = cc;
        out_mask[bl] = (c > 0) ? 1.0f : 0.0f;  // counts>0 mask (ignores padding)
    }
    __syncthreads();
    const int cnt = s_cnt;
    if ((int)threadIdx.x < cnt)
        padf[threadIdx.x] = (padding[b * SEQL + idxs[threadIdx.x]] != 0);
    __syncthreads();

    float4 acc = make_float4(0.f, 0.f, 0.f, 0.f);
    const float4* base = (const float4*)(hs + (size_t)b * SEQL * HID);
    for (int i = 0; i < cnt; ++i) {
        if (!padf[i]) {
            float4 v = base[(size_t)idxs[i] * (HID / 4) + threadIdx.x];
            acc.x += v.x; acc.y += v.y; acc.z += v.z; acc.w += v.w;
        }
    }
    acc.x *= scale; acc.y *= scale; acc.z *= scale; acc.w *= scale;
    ((float4*)(out + (size_t)bl * HID))[threadIdx.x] = acc;
}

extern "C" void kernel_launch(void* const* d_in, const int* in_sizes, int n_in,
                              void* d_out, int out_size, void* d_ws, size_t ws_size,
                              hipStream_t stream) {
    const float* hs      = (const float*)d_in[0];
    const int*   pos     = (const int*)d_in[1];
    const int*   padding = (const int*)d_in[2]; // jax bool promoted to 4-byte on device
    // d_in[3] = output_length scalar (unused; shapes fixed: 2520 -> 280, k=3)

    int* max_x  = (int*)d_ws;
    int* counts = (int*)((char*)d_ws + 256);
    int* lists  = counts + NB * OUTL;

    hipMemsetAsync(counts, 0, NB * OUTL * sizeof(int), stream);
    k_maxx <<<NB, 256, 0, stream>>>(pos, max_x);
    k_build<<<(NB * SEQL + 255) / 256, 256, 0, stream>>>(pos, max_x, counts, lists, /*k=*/3);

    float* out      = (float*)d_out;
    float* out_mask = out + (size_t)NB * OUTL * HID;
    const float scale = sqrtf((float)HID) / 9.0f;   // *sqrt(768) / k^2

    dim3 grid(OUTL, NB);
    k_pool<<<grid, 192, 0, stream>>>(hs, padding, counts, lists, out, out_mask, scale);
}

// Round 3
// 57.522 us; speedup vs baseline: 1.1537x; 1.1537x over previous
//
#include <hip/hip_runtime.h>
#include <math.h>

// VisionPooler: B=32, SEQ=2520 (84x30 grid), HIDDEN=768, OUT_LEN=280, k=3.
// out = concat( [B,280,768] pooled f32 , [B,280] mask-as-f32 ).
// 2-kernel plan:
//   k_prep (32 blocks, 1/batch): max_x reduce, bucket lists in LDS
//     (entry = (s<<1)|pad, sentinel 1), mask write. No global memset needed.
//   k_pool (280x32 blocks, 192 thr): sort 9 entries (deterministic order),
//     unrolled uniform-branch gather-accumulate, scaled float4 store.
// ws: ents[32*280*16] ints = 573,440 B.

#define NB   32
#define SEQL 2520
#define HID  768
#define OUTL 280
#define CAP  16   // slots stored per bucket (actual = 9)

__global__ void __launch_bounds__(256)
k_prep(const int* __restrict__ pos, const int* __restrict__ padding,
       int* __restrict__ ents, float* __restrict__ out_mask, int k) {
    __shared__ int red[256];
    __shared__ int s_cnt[OUTL];
    __shared__ int s_ent[OUTL * CAP];
    const int b = blockIdx.x;
    const int t = threadIdx.x;
    const int* p = pos + (size_t)b * SEQL * 2;

    // ---- max over clamped x ----
    int m = 0;
    for (int s = t; s < SEQL; s += 256) {
        int x = p[2 * s];
        if (x < 0) x = 0;
        if (x > m) m = x;
    }
    red[t] = m;
    __syncthreads();
    for (int off = 128; off > 0; off >>= 1) {
        if (t < off) { int o = red[t + off]; if (o > red[t]) red[t] = o; }
        __syncthreads();
    }
    const int mxk = (red[0] + 1) / k;

    // ---- init LDS tables ----
    for (int i = t; i < OUTL; i += 256) s_cnt[i] = 0;
    for (int i = t; i < OUTL * CAP; i += 256) s_ent[i] = 1;  // sentinel: pad bit set
    __syncthreads();

    // ---- build bucket lists (LDS atomics) ----
    const int* pd = padding + (size_t)b * SEQL;
    for (int s = t; s < SEQL; s += 256) {
        int x = p[2 * s];     if (x < 0) x = 0;
        int y = p[2 * s + 1]; if (y < 0) y = 0;
        int seg = x / k + mxk * (y / k);
        if (seg >= 0 && seg < OUTL) {   // jax segment_sum drops out-of-range ids
            int slot = atomicAdd(&s_cnt[seg], 1);
            if (slot < CAP)
                s_ent[seg * CAP + slot] = (s << 1) | (pd[s] != 0 ? 1 : 0);
        }
    }
    __syncthreads();

    // ---- flush to global ----
    int* eg = ents + (size_t)b * OUTL * CAP;
    for (int i = t; i < OUTL * CAP; i += 256) eg[i] = s_ent[i];
    for (int i = t; i < OUTL; i += 256)
        out_mask[b * OUTL + i] = (s_cnt[i] > 0) ? 1.0f : 0.0f;
}

// One block per (bucket l, batch b). 192 threads, one float4 of HID each.
__global__ void __launch_bounds__(192)
k_pool(const float* __restrict__ hs, const int* __restrict__ ents,
       float* __restrict__ out, float scale) {
    __shared__ int se[9];
    const int l = blockIdx.x;
    const int b = blockIdx.y;
    const int bl = b * OUTL + l;

    if (threadIdx.x == 0) {
        int e[9];
        const int* eg = ents + (size_t)bl * CAP;
        #pragma unroll
        for (int i = 0; i < 9; ++i) e[i] = eg[i];
        // insertion sort ascending -> deterministic summation order (by s)
        #pragma unroll
        for (int i = 1; i < 9; ++i) {
            int v = e[i], j = i - 1;
            while (j >= 0 && e[j] > v) { e[j + 1] = e[j]; --j; }
            e[j + 1] = v;
        }
        #pragma unroll
        for (int i = 0; i < 9; ++i) se[i] = e[i];
    }
    __syncthreads();

    float4 acc = make_float4(0.f, 0.f, 0.f, 0.f);
    const float4* base = (const float4*)(hs + (size_t)b * SEQL * HID);
    #pragma unroll
    for (int i = 0; i < 9; ++i) {
        int e = se[i];            // block-uniform -> no divergence
        if (!(e & 1)) {           // skip padded patches and empty slots
            float4 v = base[(size_t)(e >> 1) * (HID / 4) + threadIdx.x];
            acc.x += v.x; acc.y += v.y; acc.z += v.z; acc.w += v.w;
        }
    }
    acc.x *= scale; acc.y *= scale; acc.z *= scale; acc.w *= scale;
    ((float4*)(out + (size_t)bl * HID))[threadIdx.x] = acc;
}

extern "C" void kernel_launch(void* const* d_in, const int* in_sizes, int n_in,
                              void* d_out, int out_size, void* d_ws, size_t ws_size,
                              hipStream_t stream) {
    const float* hs      = (const float*)d_in[0];
    const int*   pos     = (const int*)d_in[1];
    const int*   padding = (const int*)d_in[2]; // jax bool -> 4-byte on device
    // d_in[3] = output_length scalar (unused; shapes fixed: 2520 -> 280, k=3)

    int* ents = (int*)d_ws;                     // [32*280*16] ints

    float* out      = (float*)d_out;
    float* out_mask = out + (size_t)NB * OUTL * HID;
    const float scale = sqrtf((float)HID) / 9.0f;   // *sqrt(768) / k^2

    k_prep<<<NB, 256, 0, stream>>>(pos, padding, ents, out_mask, /*k=*/3);
    dim3 grid(OUTL, NB);
    k_pool<<<grid, 192, 0, stream>>>(hs, ents, out, scale);
}

// Round 5
// 51.326 us; speedup vs baseline: 1.2930x; 1.1207x over previous
//
#include <hip/hip_runtime.h>
#include <math.h>

// VisionPooler: B=32, SEQ=2520 (84x30 grid), HIDDEN=768, OUT_LEN=280, k=3.
// out = concat( [B,280,768] pooled f32 , [B,280] mask-as-f32 ).
//
// k_verify (32 blocks): checks pos[b] is the regular grid (x==s%84, y==s/84).
//   regular  -> flags[b]=1 (k_pool computes bucket membership arithmetically)
//   irregular-> flags[b]=0 and builds generic bucket lists (entry=(s<<1)|pad,
//               sentinel 1) + writes mask (old k_prep behavior).
// k_pool (280x32 blocks, 192 thr): fast path derives its 9 source rows +
//   padding bits by formula (bucket l <-> (l%28, l/28)); slow path reads the
//   prebuilt lists. Uniform-branch unrolled gather, nt loads/stores.
// ws: int flags[32] @0 ; int ents[32*280*16] @128B  (573,568 B total).

#define NB    32
#define SEQL  2520
#define HID   768
#define OUTL  280
#define CAP   16
#define GX    84      // grid x extent when regular
#define KP    3       // pool factor
#define MXK   (GX / KP)   // 28 buckets per row when regular

typedef float f32x4 __attribute__((ext_vector_type(4)));

__global__ void __launch_bounds__(256)
k_verify(const int* __restrict__ pos, const int* __restrict__ padding,
         int* __restrict__ flags, int* __restrict__ ents,
         float* __restrict__ out_mask) {
    __shared__ int r_ok[256];
    __shared__ int r_mx[256];
    __shared__ int s_cnt[OUTL];
    __shared__ int s_ent[OUTL * CAP];
    const int b = blockIdx.x;
    const int t = threadIdx.x;
    const int* p = pos + (size_t)b * SEQL * 2;

    int ok = 1, m = 0;
    for (int s = t; s < SEQL; s += 256) {
        int x = p[2 * s], y = p[2 * s + 1];
        ok &= (x == s % GX) & (y == s / GX);
        int cx = x < 0 ? 0 : x;
        if (cx > m) m = cx;
    }
    r_ok[t] = ok; r_mx[t] = m;
    __syncthreads();
    for (int off = 128; off > 0; off >>= 1) {
        if (t < off) {
            r_ok[t] &= r_ok[t + off];
            int o = r_mx[t + off]; if (o > r_mx[t]) r_mx[t] = o;
        }
        __syncthreads();
    }
    if (r_ok[0]) {                       // regular grid: nothing else needed
        if (t == 0) flags[b] = 1;
        return;
    }

    // ---- generic fallback: build bucket lists ----
    const int mxk = (r_mx[0] + 1) / KP;
    for (int i = t; i < OUTL; i += 256) s_cnt[i] = 0;
    for (int i = t; i < OUTL * CAP; i += 256) s_ent[i] = 1;  // sentinel: pad bit
    __syncthreads();
    const int* pd = padding + (size_t)b * SEQL;
    for (int s = t; s < SEQL; s += 256) {
        int x = p[2 * s];     if (x < 0) x = 0;
        int y = p[2 * s + 1]; if (y < 0) y = 0;
        int seg = x / KP + mxk * (y / KP);
        if (seg >= 0 && seg < OUTL) {    // jax segment_sum drops out-of-range
            int slot = atomicAdd(&s_cnt[seg], 1);
            if (slot < CAP)
                s_ent[seg * CAP + slot] = (s << 1) | (pd[s] != 0 ? 1 : 0);
        }
    }
    __syncthreads();
    int* eg = ents + (size_t)b * OUTL * CAP;
    for (int i = t; i < OUTL * CAP; i += 256) eg[i] = s_ent[i];
    for (int i = t; i < OUTL; i += 256)
        out_mask[b * OUTL + i] = (s_cnt[i] > 0) ? 1.0f : 0.0f;
    if (t == 0) flags[b] = 0;
}

// One block per (bucket l, batch b). 192 threads, one float4 of HID each.
__global__ void __launch_bounds__(192)
k_pool(const float* __restrict__ hs, const int* __restrict__ padding,
       const int* __restrict__ flags, const int* __restrict__ ents,
       float* __restrict__ out, float* __restrict__ out_mask, float scale) {
    __shared__ int se[9];
    const int l = blockIdx.x;
    const int b = blockIdx.y;
    const int bl = b * OUTL + l;

    if (flags[b]) {
        // regular: bucket l <-> (xk,yk)=(l%MXK, l/MXK); 9 sources by formula
        if ((int)threadIdx.x < 9) {
            int dy = threadIdx.x / 3, dx = threadIdx.x - 3 * dy;
            int s = (KP * (l / MXK) + dy) * GX + KP * (l % MXK) + dx;
            se[threadIdx.x] = (s << 1) | (padding[b * SEQL + s] != 0 ? 1 : 0);
        }
        if (threadIdx.x == 0) out_mask[bl] = 1.0f;  // every bucket gets 9 patches
    } else if (threadIdx.x == 0) {
        int e[9];
        const int* eg = ents + (size_t)bl * CAP;
        #pragma unroll
        for (int i = 0; i < 9; ++i) e[i] = eg[i];
        #pragma unroll
        for (int i = 1; i < 9; ++i) {     // sort ascending: deterministic order
            int v = e[i], j = i - 1;
            while (j >= 0 && e[j] > v) { e[j + 1] = e[j]; --j; }
            e[j + 1] = v;
        }
        #pragma unroll
        for (int i = 0; i < 9; ++i) se[i] = e[i];
        // mask already written by k_verify in this case
    }
    __syncthreads();

    f32x4 acc = (f32x4)(0.f);
    const f32x4* base = (const f32x4*)(hs + (size_t)b * SEQL * HID);
    #pragma unroll
    for (int i = 0; i < 9; ++i) {
        int e = se[i];            // block-uniform -> no divergence
        if (!(e & 1)) {           // skip padded patches and empty slots
            f32x4 v = __builtin_nontemporal_load(
                base + (size_t)(e >> 1) * (HID / 4) + threadIdx.x);
            acc += v;
        }
    }
    acc *= scale;
    __builtin_nontemporal_store(acc,
        (f32x4*)(out + (size_t)bl * HID) + threadIdx.x);
}

extern "C" void kernel_launch(void* const* d_in, const int* in_sizes, int n_in,
                              void* d_out, int out_size, void* d_ws, size_t ws_size,
                              hipStream_t stream) {
    const float* hs      = (const float*)d_in[0];
    const int*   pos     = (const int*)d_in[1];
    const int*   padding = (const int*)d_in[2]; // jax bool -> 4-byte on device
    // d_in[3] = output_length scalar (unused; shapes fixed: 2520 -> 280, k=3)

    int* flags = (int*)d_ws;                    // [32]
    int* ents  = (int*)((char*)d_ws + 128);     // [32*280*16]

    float* out      = (float*)d_out;
    float* out_mask = out + (size_t)NB * OUTL * HID;
    const float scale = sqrtf((float)HID) / 9.0f;   // *sqrt(768) / k^2

    k_verify<<<NB, 256, 0, stream>>>(pos, padding, flags, ents, out_mask);
    dim3 grid(OUTL, NB);
    k_pool<<<grid, 192, 0, stream>>>(hs, padding, flags, ents, out, out_mask, scale);
}